// Round 4
// baseline (743.750 us; speedup 1.0000x reference)
//
#include <hip/hip_runtime.h>
#include <hip/hip_bf16.h>

// MHA forward: B=2, N=4096, E=768, H=8, D=96.
// Precision scheme: Q,K path is split-bf16 (hi+lo) end-to-end so energy is
// ~f32-exact (softmax exponentiates absolute energy error); V/P/out-proj bf16.

typedef unsigned short u16;
typedef __attribute__((ext_vector_type(4))) float f32x4;
typedef __attribute__((ext_vector_type(8))) __bf16 bf16x8;
typedef __attribute__((ext_vector_type(8))) u16 u16x8;

#define DEVI static __device__ __forceinline__

DEVI u16 f2bf(float f) {
  union { float f; unsigned u; } v; v.f = f;
  unsigned r = v.u + 0x7FFFu + ((v.u >> 16) & 1u);   // RNE
  return (u16)(r >> 16);
}
DEVI float bf2f(u16 h) {
  union { unsigned u; float f; } v; v.u = ((unsigned)h) << 16;
  return v.f;
}

DEVI f32x4 mfma16(u16x8 a, u16x8 b, f32x4 c) {
  return __builtin_amdgcn_mfma_f32_16x16x32_bf16(
      __builtin_bit_cast(bf16x8, a), __builtin_bit_cast(bf16x8, b), c, 0, 0, 0);
}

// ---------------- cast x -> A_ext = [xh | xl], row stride 1536 ----------------
__global__ void k_cast(const float* __restrict__ x, u16* __restrict__ ax, int n8) {
  int i = blockIdx.x * blockDim.x + threadIdx.x;
  if (i >= n8) return;
  const f32x4* p = (const f32x4*)x + (size_t)i * 2;
  f32x4 a = p[0], b = p[1];
  u16x8 oh, ol;
  #pragma unroll
  for (int u = 0; u < 4; ++u) {
    oh[u] = f2bf(a[u]); ol[u] = f2bf(a[u] - bf2f(oh[u]));
    oh[4 + u] = f2bf(b[u]); ol[4 + u] = f2bf(b[u] - bf2f(oh[4 + u]));
  }
  int row = i / 96, cc = i % 96;                   // 96 chunks of 8 per 768-row
  u16* base = ax + (size_t)row * 1536 + cc * 8;
  *(u16x8*)base = oh;
  *(u16x8*)(base + 768) = ol;
}

// ------------- weight transpose+cast -------------
// Wq,Wk -> ext layout [768 n][2304]: [WhT | WhT | WlT]; Wv,Wo -> plain WhT [768][768]
__global__ void k_wt(const float* __restrict__ Wq, const float* __restrict__ Wk,
                     const float* __restrict__ Wv, const float* __restrict__ Wo,
                     u16* __restrict__ wqkT, u16* __restrict__ wvT,
                     u16* __restrict__ woT) {
  __shared__ __align__(16) float T[64 * 68];
  int bid = blockIdx.x;
  int mat = bid / 144, tt = bid % 144;
  int tr = tt / 12, tc = tt % 12;            // tr: k-tile, tc: n-tile
  const float* W = (mat == 0) ? Wq : (mat == 1) ? Wk : (mat == 2) ? Wv : Wo;
  int k0 = tr * 64, n0 = tc * 64;
  int t = threadIdx.x;
  #pragma unroll
  for (int ii = 0; ii < 4; ++ii) {            // 64 rows x 16 f32x4 chunks
    int i = t + 256 * ii, r = i >> 4, c4 = i & 15;
    f32x4 v = *(const f32x4*)(W + (size_t)(k0 + r) * 768 + n0 + c4 * 4);
    *(f32x4*)(&T[r * 68 + c4 * 4]) = v;
  }
  __syncthreads();
  #pragma unroll
  for (int ii = 0; ii < 2; ++ii) {            // 64 n-rows x 8 k-chunks(8)
    int i = t + 256 * ii, nn = i & 63, kc8 = i >> 6;
    u16x8 oh, ol;
    #pragma unroll
    for (int u = 0; u < 8; ++u) {
      float w = T[(kc8 * 8 + u) * 68 + nn];
      oh[u] = f2bf(w); ol[u] = f2bf(w - bf2f(oh[u]));
    }
    if (mat < 2) {
      u16* dst = wqkT + (size_t)mat * 768 * 2304 +
                 (size_t)(n0 + nn) * 2304 + k0 + kc8 * 8;
      *(u16x8*)dst = oh;            // pairs xh
      *(u16x8*)(dst + 768) = oh;    // pairs xl
      *(u16x8*)(dst + 1536) = ol;   // pairs xh
    } else {
      u16* dst = ((mat == 2) ? wvT : woT) + (size_t)(n0 + nn) * 768 + k0 + kc8 * 8;
      *(u16x8*)dst = oh;
    }
  }
}

// ------------- V [BH][N][D] -> Vt [BH][D][N] (bf16) -------------
__global__ void k_vt(const u16* __restrict__ V, u16* __restrict__ Vt) {
  __shared__ __align__(16) u16 L[64 * 104];
  int bid = blockIdx.x, bh = bid >> 6, nb = bid & 63;
  int n0 = nb * 64, t = threadIdx.x;
  const u16* src = V + ((size_t)bh * 4096 + n0) * 96;
  #pragma unroll
  for (int ii = 0; ii < 3; ++ii) {
    int i = t + 256 * ii, r = i / 12, c8 = i % 12;
    *(u16x8*)(&L[r * 104 + c8 * 8]) = *(const u16x8*)(src + (size_t)i * 8);
  }
  __syncthreads();
  #pragma unroll
  for (int jj = 0; jj < 3; ++jj) {
    int d = (t & 31) + 32 * jj, c8 = t >> 5;
    u16x8 o;
    #pragma unroll
    for (int u = 0; u < 8; ++u) o[u] = L[(c8 * 8 + u) * 104 + d];
    *(u16x8*)(Vt + ((size_t)bh * 96 + d) * 4096 + n0 + c8 * 8) = o;
  }
}

// ------------- GEMM: 128x128 tile, BK=32, 4 waves, 16x16x32 bf16 MFMA -------------
// MODE 0: QK-ext  A[8192][1536](wrap k>=1536 -> k-1536), BT[1536 n][2304], kdim=2304
//         -> writes Qh,Ql,Kh,Kl [B,H,N,D] bf16 (+bias, hi/lo split)
// MODE 1: V       A[8192][1536] (first 768 cols), BT=wvT[768][768], kdim=768 -> Vb bf16
// MODE 2: outproj A=attnb[8192][768], BT=woT[768][768], kdim=768 -> f32 Out
template <int MODE>
__global__ __launch_bounds__(256) void k_gemm(
    const u16* __restrict__ A, const u16* __restrict__ BT,
    const float* __restrict__ bias0, const float* __restrict__ bias1,
    u16* __restrict__ D0h, u16* __restrict__ D0l,
    u16* __restrict__ D1h, u16* __restrict__ D1l,
    float* __restrict__ Out) {
  __shared__ __align__(16) u16 Alds[128 * 56];
  __shared__ __align__(16) u16 Blds[128 * 56];
  const int kdim = (MODE == 0) ? 2304 : 768;
  const int lda = (MODE == 2) ? 768 : 1536;
  const int ldb = (MODE == 0) ? 2304 : 768;
  const int m0 = blockIdx.x * 128, n0 = blockIdx.y * 128;
  const int t = threadIdx.x, w = t >> 6, lane = t & 63;
  const int g = lane >> 4, c = lane & 15;
  const int wr = w >> 1, wc = w & 1;

  f32x4 acc[4][4] = {};

  for (int k0 = 0; k0 < kdim; k0 += 32) {
    const int ka = (MODE == 0 && k0 >= 1536) ? k0 - 1536 : k0;  // xh again
    __syncthreads();
    #pragma unroll
    for (int ii = 0; ii < 2; ++ii) {
      int i = t + 256 * ii, r = i >> 2, c8 = i & 3;
      *(u16x8*)(&Alds[r * 56 + c8 * 8]) =
          *(const u16x8*)(A + (size_t)(m0 + r) * lda + ka + c8 * 8);
      *(u16x8*)(&Blds[r * 56 + c8 * 8]) =
          *(const u16x8*)(BT + (size_t)(n0 + r) * ldb + k0 + c8 * 8);
    }
    __syncthreads();
    u16x8 af[4], bf[4];
    #pragma unroll
    for (int mt = 0; mt < 4; ++mt)
      af[mt] = *(u16x8*)(&Alds[(wr * 64 + mt * 16 + c) * 56 + g * 8]);
    #pragma unroll
    for (int nt = 0; nt < 4; ++nt)
      bf[nt] = *(u16x8*)(&Blds[(wc * 64 + nt * 16 + c) * 56 + g * 8]);
    #pragma unroll
    for (int mt = 0; mt < 4; ++mt)
      #pragma unroll
      for (int nt = 0; nt < 4; ++nt)
        acc[mt][nt] = mfma16(af[mt], bf[nt], acc[mt][nt]);
  }

  // C layout per 16x16 tile: col = lane&15, row = (lane>>4)*4 + reg  [m89/m91]
  if (MODE == 0) {
    const int mat = (n0 >= 768);                   // 0: Q cols, 1: K cols
    const float* bias = mat ? bias1 : bias0;
    u16* dsth = mat ? D1h : D0h;
    u16* dstl = mat ? D1l : D0l;
    const int nbase = n0 - mat * 768;
    #pragma unroll
    for (int mt = 0; mt < 4; ++mt)
      #pragma unroll
      for (int nt = 0; nt < 4; ++nt) {
        int ncol = nbase + wc * 64 + nt * 16 + c;
        int h = ncol / 96, d = ncol % 96;
        float bi = bias[ncol];
        #pragma unroll
        for (int r = 0; r < 4; ++r) {
          int mrow = m0 + wr * 64 + mt * 16 + g * 4 + r;
          int b = mrow >> 12, ntok = mrow & 4095;
          size_t idx = ((size_t)((b * 8 + h) * 4096 + ntok)) * 96 + d;
          float val = acc[mt][nt][r] + bi;
          u16 hi = f2bf(val);
          dsth[idx] = hi;
          dstl[idx] = f2bf(val - bf2f(hi));
        }
      }
  } else if (MODE == 1) {
    #pragma unroll
    for (int mt = 0; mt < 4; ++mt)
      #pragma unroll
      for (int nt = 0; nt < 4; ++nt) {
        int ncol = n0 + wc * 64 + nt * 16 + c;
        int h = ncol / 96, d = ncol % 96;
        float bi = bias0[ncol];
        #pragma unroll
        for (int r = 0; r < 4; ++r) {
          int mrow = m0 + wr * 64 + mt * 16 + g * 4 + r;
          int b = mrow >> 12, ntok = mrow & 4095;
          D0h[((size_t)((b * 8 + h) * 4096 + ntok)) * 96 + d] =
              f2bf(acc[mt][nt][r] + bi);
        }
      }
  } else {
    #pragma unroll
    for (int mt = 0; mt < 4; ++mt)
      #pragma unroll
      for (int nt = 0; nt < 4; ++nt) {
        int ncol = n0 + wc * 64 + nt * 16 + c;
        float bi = bias0[ncol];
        #pragma unroll
        for (int r = 0; r < 4; ++r) {
          int mrow = m0 + wr * 64 + mt * 16 + g * 4 + r;
          Out[(size_t)mrow * 768 + ncol] = acc[mt][nt][r] + bi;
        }
      }
  }
}

// ------------- flash attention, transposed-energy, split-bf16 QK^T -------------
// block = 4 waves x 16 q-rows = 64 q; KV tiles of 64 staged in LDS.
// E = Qh.Kh + Ql.Kh + Qh.Kl (f32-exact energy); lane owns one q-col -> scalar m,s.
__global__ __launch_bounds__(256) void k_attn(
    const u16* __restrict__ Qh, const u16* __restrict__ Ql,
    const u16* __restrict__ Kh, const u16* __restrict__ Kl,
    const u16* __restrict__ Vt, u16* __restrict__ attn) {
  __shared__ __align__(16) u16 Khlds[64 * 104];  // reused as O_lds in epilogue
  __shared__ __align__(16) u16 Kllds[64 * 104];
  __shared__ __align__(16) u16 Vtlds[96 * 72];
  __shared__ __align__(16) u16 Plds[4][16 * 72]; // per-wave P tile [16 q][64 k]

  const int bid = blockIdx.x;
  const int bh = bid >> 6, qb = bid & 63;
  const int t = threadIdx.x, w = t >> 6, lane = t & 63;
  const int g = lane >> 4, c = lane & 15;
  const int q0 = qb * 64;

  // Q fragments (B-operand: lane holds Q[q=c][d-chunk]) hi+lo
  u16x8 qfh[3], qfl[3];
  const size_t qoff = ((size_t)bh * 4096 + q0 + w * 16 + c) * 96;
  #pragma unroll
  for (int kc = 0; kc < 3; ++kc) {
    qfh[kc] = *(const u16x8*)(Qh + qoff + kc * 32 + g * 8);
    qfl[kc] = *(const u16x8*)(Ql + qoff + kc * 32 + g * 8);
  }

  f32x4 acc_o[6] = {};                 // out^T[d = dt*16+g*4+r][q = c]
  float m = -1e30f, s = 0.f;

  const u16* Khb = Kh + (size_t)bh * 4096 * 96;
  const u16* Klb = Kl + (size_t)bh * 4096 * 96;
  const u16* Vtb = Vt + (size_t)bh * 96 * 4096;

  #pragma unroll 1
  for (int kv0 = 0; kv0 < 4096; kv0 += 64) {
    __syncthreads();
    {
      #pragma unroll
      for (int ii = 0; ii < 3; ++ii) {        // K tiles [64][96] -> [64][104]
        int i = t + 256 * ii, r = i / 12, c8 = i % 12;
        size_t goff = (size_t)kv0 * 96 + (size_t)i * 8;
        *(u16x8*)(&Khlds[r * 104 + c8 * 8]) = *(const u16x8*)(Khb + goff);
        *(u16x8*)(&Kllds[r * 104 + c8 * 8]) = *(const u16x8*)(Klb + goff);
      }
      #pragma unroll
      for (int ii = 0; ii < 3; ++ii) {        // Vt tile [96][64] -> [96][72]
        int i = t + 256 * ii, d = i >> 3, c8 = i & 7;
        *(u16x8*)(&Vtlds[d * 72 + c8 * 8]) =
            *(const u16x8*)(Vtb + (size_t)d * 4096 + kv0 + c8 * 8);
      }
    }
    __syncthreads();

    // energy^T: et[mt] holds E^T[k = mt*16 + g*4 + r][q = c]
    f32x4 et[4] = {};
    #pragma unroll
    for (int kc = 0; kc < 3; ++kc)
      #pragma unroll
      for (int mt = 0; mt < 4; ++mt) {
        u16x8 kfh = *(u16x8*)(&Khlds[(mt * 16 + c) * 104 + kc * 32 + g * 8]);
        u16x8 kfl = *(u16x8*)(&Kllds[(mt * 16 + c) * 104 + kc * 32 + g * 8]);
        et[mt] = mfma16(kfh, qfh[kc], et[mt]);
        et[mt] = mfma16(kfh, qfl[kc], et[mt]);
        et[mt] = mfma16(kfl, qfh[kc], et[mt]);
      }

    // online softmax over k; per-lane scalar state (q = c fixed per lane)
    float tmax = -1e30f;
    #pragma unroll
    for (int mt = 0; mt < 4; ++mt)
      #pragma unroll
      for (int r = 0; r < 4; ++r) tmax = fmaxf(tmax, et[mt][r]);
    tmax = fmaxf(tmax, __shfl_xor(tmax, 16));
    tmax = fmaxf(tmax, __shfl_xor(tmax, 32));
    float mnew = fmaxf(m, tmax);
    float scale = __expf(m - mnew);
    float psum = 0.f;
    #pragma unroll
    for (int mt = 0; mt < 4; ++mt)
      #pragma unroll
      for (int r = 0; r < 4; ++r) {
        float p = __expf(et[mt][r] - mnew);
        et[mt][r] = p; psum += p;
      }
    psum += __shfl_xor(psum, 16);
    psum += __shfl_xor(psum, 32);
    s = s * scale + psum;
    m = mnew;
    #pragma unroll
    for (int dt = 0; dt < 6; ++dt)
      #pragma unroll
      for (int r = 0; r < 4; ++r) acc_o[dt][r] *= scale;

    // P (bf16) -> per-wave LDS [16 q][64 k], packed u32 pairs along k
    u16* P = &Plds[w][0];
    #pragma unroll
    for (int mt = 0; mt < 4; ++mt)
      #pragma unroll
      for (int rp = 0; rp < 2; ++rp) {
        unsigned pk = (unsigned)f2bf(et[mt][2 * rp]) |
                      ((unsigned)f2bf(et[mt][2 * rp + 1]) << 16);
        *(unsigned*)(&P[c * 72 + mt * 16 + g * 4 + 2 * rp]) = pk;
      }
    // PV B-fragments: lane holds P[k = kb*32+g*8+j][q = c]
    u16x8 pf[2];
    #pragma unroll
    for (int kb = 0; kb < 2; ++kb)
      pf[kb] = *(u16x8*)(&P[c * 72 + kb * 32 + g * 8]);
    // out^T += V^T * P
    #pragma unroll
    for (int dt = 0; dt < 6; ++dt)
      #pragma unroll
      for (int kb = 0; kb < 2; ++kb) {
        u16x8 vf = *(u16x8*)(&Vtlds[(dt * 16 + c) * 72 + kb * 32 + g * 8]);
        acc_o[dt] = mfma16(vf, pf[kb], acc_o[dt]);
      }
  }

  // reference: att = softmax(E)/sqrt(D)  ->  out = (O/s)/sqrt(96)
  const float inv = 1.0f / (s * 9.797958971132712f);
  __syncthreads();
  u16* O = Khlds;  // reuse as [64 q][96 d] with stride 104
  #pragma unroll
  for (int dt = 0; dt < 6; ++dt)
    #pragma unroll
    for (int rp = 0; rp < 2; ++rp) {
      unsigned pk = (unsigned)f2bf(acc_o[dt][2 * rp] * inv) |
                    ((unsigned)f2bf(acc_o[dt][2 * rp + 1] * inv) << 16);
      *(unsigned*)(&O[(w * 16 + c) * 104 + dt * 16 + g * 4 + 2 * rp]) = pk;
    }
  __syncthreads();
  const int b = bh >> 3, h = bh & 7;
  #pragma unroll
  for (int ii = 0; ii < 3; ++ii) {
    int i = t + 256 * ii, r = i / 12, c8 = i % 12;
    u16x8 v = *(u16x8*)(&O[r * 104 + c8 * 8]);
    *(u16x8*)(attn + ((size_t)(b * 4096 + q0 + r)) * 768 + h * 96 + c8 * 8) = v;
  }
}

// ---------------------------------------------------------------------
extern "C" void kernel_launch(void* const* d_in, const int* in_sizes, int n_in,
                              void* d_out, int out_size, void* d_ws, size_t ws_size,
                              hipStream_t stream) {
  const float* x  = (const float*)d_in[0];
  const float* Wq = (const float*)d_in[1];
  const float* bq = (const float*)d_in[2];
  const float* Wk = (const float*)d_in[3];
  const float* bk = (const float*)d_in[4];
  const float* Wv = (const float*)d_in[5];
  const float* bv = (const float*)d_in[6];
  const float* Wo = (const float*)d_in[7];
  const float* bo = (const float*)d_in[8];
  float* out = (float*)d_out;

  char* ws = (char*)d_ws;
  size_t off = 0;
  auto alloc = [&](size_t bytes) {
    void* p = ws + off;
    off += (bytes + 1023) & ~(size_t)1023;
    return p;
  };
  const size_t SZ = (size_t)16 * 4096 * 96 * 2;      // 12.6 MB per [B,H,N,D] bf16
  u16* ax    = (u16*)alloc((size_t)8192 * 1536 * 2); // [xh | xl]  24 MB
  u16* wqkT  = (u16*)alloc((size_t)2 * 768 * 2304 * 2);
  u16* wvT   = (u16*)alloc((size_t)768 * 768 * 2);
  u16* woT   = (u16*)alloc((size_t)768 * 768 * 2);
  u16* Qhb   = (u16*)alloc(SZ);
  u16* Qlb   = (u16*)alloc(SZ);
  u16* Khb   = (u16*)alloc(SZ);
  u16* Klb   = (u16*)alloc(SZ);
  u16* Vb    = (u16*)alloc(SZ);
  u16* Vtb   = (u16*)alloc(SZ);
  u16* attnb = (u16*)alloc(SZ);
  (void)ws_size; (void)in_sizes; (void)n_in; (void)out_size;
  // total ws use ~122 MB

  k_cast<<<3072, 256, 0, stream>>>(x, ax, 786432);
  k_wt<<<576, 256, 0, stream>>>(Wq, Wk, Wv, Wo, wqkT, wvT, woT);
  // QK ext GEMM: N = 1536 cols (Q | K), K = 2304
  k_gemm<0><<<dim3(64, 12), 256, 0, stream>>>(ax, wqkT, bq, bk,
                                              Qhb, Qlb, Khb, Klb, nullptr);
  // V GEMM: K = 768 (xh slice of ax)
  k_gemm<1><<<dim3(64, 6), 256, 0, stream>>>(ax, wvT, bv, nullptr,
                                             Vb, nullptr, nullptr, nullptr, nullptr);
  k_vt<<<1024, 256, 0, stream>>>(Vb, Vtb);
  k_attn<<<1024, 256, 0, stream>>>(Qhb, Qlb, Khb, Klb, Vtb, attnb);
  k_gemm<2><<<dim3(64, 6), 256, 0, stream>>>(attnb, woT, bo, nullptr,
                                             nullptr, nullptr, nullptr, nullptr, out);
}

// Round 5
// 443.846 us; speedup vs baseline: 1.6757x; 1.6757x over previous
//
#include <hip/hip_runtime.h>
#include <hip/hip_bf16.h>

// MHA forward: B=2, N=4096, E=768, H=8, D=96.
// Q,K path split-bf16 (hi+lo) end-to-end -> ~f32-exact energy; V/P/out-proj bf16.
// R5: attn QBLK=128 (4 waves x 32q), global_load_lds staging, swizzled Vt tile.

typedef unsigned short u16;
typedef __attribute__((ext_vector_type(4))) float f32x4;
typedef __attribute__((ext_vector_type(8))) __bf16 bf16x8;
typedef __attribute__((ext_vector_type(8))) u16 u16x8;

#define DEVI static __device__ __forceinline__

// global->LDS DMA, 16B per lane; LDS dest = wave-uniform base + lane*16 (m104)
#define GLD16(gp, lp)                                                          \
  __builtin_amdgcn_global_load_lds(                                            \
      (const __attribute__((address_space(1))) void*)(gp),                     \
      (__attribute__((address_space(3))) void*)(lp), 16, 0, 0)

DEVI u16 f2bf(float f) {
  union { float f; unsigned u; } v; v.f = f;
  unsigned r = v.u + 0x7FFFu + ((v.u >> 16) & 1u);   // RNE
  return (u16)(r >> 16);
}
DEVI float bf2f(u16 h) {
  union { unsigned u; float f; } v; v.u = ((unsigned)h) << 16;
  return v.f;
}

DEVI f32x4 mfma16(u16x8 a, u16x8 b, f32x4 c) {
  return __builtin_amdgcn_mfma_f32_16x16x32_bf16(
      __builtin_bit_cast(bf16x8, a), __builtin_bit_cast(bf16x8, b), c, 0, 0, 0);
}

// ---------------- cast x -> A_ext = [xh | xl], row stride 1536 ----------------
__global__ void k_cast(const float* __restrict__ x, u16* __restrict__ ax, int n8) {
  int i = blockIdx.x * blockDim.x + threadIdx.x;
  if (i >= n8) return;
  const f32x4* p = (const f32x4*)x + (size_t)i * 2;
  f32x4 a = p[0], b = p[1];
  u16x8 oh, ol;
  #pragma unroll
  for (int u = 0; u < 4; ++u) {
    oh[u] = f2bf(a[u]); ol[u] = f2bf(a[u] - bf2f(oh[u]));
    oh[4 + u] = f2bf(b[u]); ol[4 + u] = f2bf(b[u] - bf2f(oh[4 + u]));
  }
  int row = i / 96, cc = i % 96;
  u16* base = ax + (size_t)row * 1536 + cc * 8;
  *(u16x8*)base = oh;
  *(u16x8*)(base + 768) = ol;
}

// ------------- weight transpose+cast -------------
// Wq,Wk -> ext layout [768 n][2304]: [WhT | WhT | WlT]; Wv,Wo -> plain WhT [768][768]
__global__ void k_wt(const float* __restrict__ Wq, const float* __restrict__ Wk,
                     const float* __restrict__ Wv, const float* __restrict__ Wo,
                     u16* __restrict__ wqkT, u16* __restrict__ wvT,
                     u16* __restrict__ woT) {
  __shared__ __align__(16) float T[64 * 68];
  int bid = blockIdx.x;
  int mat = bid / 144, tt = bid % 144;
  int tr = tt / 12, tc = tt % 12;
  const float* W = (mat == 0) ? Wq : (mat == 1) ? Wk : (mat == 2) ? Wv : Wo;
  int k0 = tr * 64, n0 = tc * 64;
  int t = threadIdx.x;
  #pragma unroll
  for (int ii = 0; ii < 4; ++ii) {
    int i = t + 256 * ii, r = i >> 4, c4 = i & 15;
    f32x4 v = *(const f32x4*)(W + (size_t)(k0 + r) * 768 + n0 + c4 * 4);
    *(f32x4*)(&T[r * 68 + c4 * 4]) = v;
  }
  __syncthreads();
  #pragma unroll
  for (int ii = 0; ii < 2; ++ii) {
    int i = t + 256 * ii, nn = i & 63, kc8 = i >> 6;
    u16x8 oh, ol;
    #pragma unroll
    for (int u = 0; u < 8; ++u) {
      float w = T[(kc8 * 8 + u) * 68 + nn];
      oh[u] = f2bf(w); ol[u] = f2bf(w - bf2f(oh[u]));
    }
    if (mat < 2) {
      u16* dst = wqkT + (size_t)mat * 768 * 2304 +
                 (size_t)(n0 + nn) * 2304 + k0 + kc8 * 8;
      *(u16x8*)dst = oh;
      *(u16x8*)(dst + 768) = oh;
      *(u16x8*)(dst + 1536) = ol;
    } else {
      u16* dst = ((mat == 2) ? wvT : woT) + (size_t)(n0 + nn) * 768 + k0 + kc8 * 8;
      *(u16x8*)dst = oh;
    }
  }
}

// ------------- V [BH][N][D] -> Vt [BH][D][N] (bf16) -------------
__global__ void k_vt(const u16* __restrict__ V, u16* __restrict__ Vt) {
  __shared__ __align__(16) u16 L[64 * 104];
  int bid = blockIdx.x, bh = bid >> 6, nb = bid & 63;
  int n0 = nb * 64, t = threadIdx.x;
  const u16* src = V + ((size_t)bh * 4096 + n0) * 96;
  #pragma unroll
  for (int ii = 0; ii < 3; ++ii) {
    int i = t + 256 * ii, r = i / 12, c8 = i % 12;
    *(u16x8*)(&L[r * 104 + c8 * 8]) = *(const u16x8*)(src + (size_t)i * 8);
  }
  __syncthreads();
  #pragma unroll
  for (int jj = 0; jj < 3; ++jj) {
    int d = (t & 31) + 32 * jj, c8 = t >> 5;
    u16x8 o;
    #pragma unroll
    for (int u = 0; u < 8; ++u) o[u] = L[(c8 * 8 + u) * 104 + d];
    *(u16x8*)(Vt + ((size_t)bh * 96 + d) * 4096 + n0 + c8 * 8) = o;
  }
}

// ------------- GEMM: 128x128 tile, BK=32, 4 waves, DMA staging -------------
// MODE 0: QK-ext  A[8192][1536](wrap k>=1536), BT[1536 n][2304], kdim=2304
// MODE 1: V       A(xh cols), BT=wvT[768][768], kdim=768 -> Vb bf16
// MODE 2: outproj A=attnb[8192][768], BT=woT[768][768], kdim=768 -> f32 Out
template <int MODE>
__global__ __launch_bounds__(256) void k_gemm(
    const u16* __restrict__ A, const u16* __restrict__ BT,
    const float* __restrict__ bias0, const float* __restrict__ bias1,
    u16* __restrict__ D0h, u16* __restrict__ D0l,
    u16* __restrict__ D1h, u16* __restrict__ D1l,
    float* __restrict__ Out) {
  __shared__ __align__(16) u16 Alds[128 * 32];   // linear, DMA-staged
  __shared__ __align__(16) u16 Blds[128 * 32];
  const int kdim = (MODE == 0) ? 2304 : 768;
  const int lda = (MODE == 2) ? 768 : 1536;
  const int ldb = (MODE == 0) ? 2304 : 768;
  const int m0 = blockIdx.x * 128, n0 = blockIdx.y * 128;
  const int t = threadIdx.x, w = t >> 6, lane = t & 63;
  const int g = lane >> 4, c = lane & 15;
  const int wr = w >> 1, wc = w & 1;

  f32x4 acc[4][4] = {};

  for (int k0 = 0; k0 < kdim; k0 += 32) {
    const int ka = (MODE == 0 && k0 >= 1536) ? k0 - 1536 : k0;
    __syncthreads();
    #pragma unroll
    for (int ii = 0; ii < 2; ++ii) {
      int i = t + 256 * ii;                 // 16B chunk id; row = i>>2, c8 = i&3
      int lbase = (i & ~63) * 8;            // wave-uniform u16 offset
      GLD16(A + (size_t)(m0 + (i >> 2)) * lda + ka + (i & 3) * 8, &Alds[lbase]);
      GLD16(BT + (size_t)(n0 + (i >> 2)) * ldb + k0 + (i & 3) * 8, &Blds[lbase]);
    }
    __syncthreads();
    u16x8 af[4], bf[4];
    #pragma unroll
    for (int mt = 0; mt < 4; ++mt)
      af[mt] = *(u16x8*)(&Alds[(wr * 64 + mt * 16 + c) * 32 + g * 8]);
    #pragma unroll
    for (int nt = 0; nt < 4; ++nt)
      bf[nt] = *(u16x8*)(&Blds[(wc * 64 + nt * 16 + c) * 32 + g * 8]);
    #pragma unroll
    for (int mt = 0; mt < 4; ++mt)
      #pragma unroll
      for (int nt = 0; nt < 4; ++nt)
        acc[mt][nt] = mfma16(af[mt], bf[nt], acc[mt][nt]);
  }

  // C layout per 16x16 tile: col = lane&15, row = (lane>>4)*4 + reg  [m89/m91]
  if (MODE == 0) {
    const int mat = (n0 >= 768);
    const float* bias = mat ? bias1 : bias0;
    u16* dsth = mat ? D1h : D0h;
    u16* dstl = mat ? D1l : D0l;
    const int nbase = n0 - mat * 768;
    #pragma unroll
    for (int mt = 0; mt < 4; ++mt)
      #pragma unroll
      for (int nt = 0; nt < 4; ++nt) {
        int ncol = nbase + wc * 64 + nt * 16 + c;
        int h = ncol / 96, d = ncol % 96;
        float bi = bias[ncol];
        #pragma unroll
        for (int r = 0; r < 4; ++r) {
          int mrow = m0 + wr * 64 + mt * 16 + g * 4 + r;
          int b = mrow >> 12, ntok = mrow & 4095;
          size_t idx = ((size_t)((b * 8 + h) * 4096 + ntok)) * 96 + d;
          float val = acc[mt][nt][r] + bi;
          u16 hi = f2bf(val);
          dsth[idx] = hi;
          dstl[idx] = f2bf(val - bf2f(hi));
        }
      }
  } else if (MODE == 1) {
    #pragma unroll
    for (int mt = 0; mt < 4; ++mt)
      #pragma unroll
      for (int nt = 0; nt < 4; ++nt) {
        int ncol = n0 + wc * 64 + nt * 16 + c;
        int h = ncol / 96, d = ncol % 96;
        float bi = bias0[ncol];
        #pragma unroll
        for (int r = 0; r < 4; ++r) {
          int mrow = m0 + wr * 64 + mt * 16 + g * 4 + r;
          int b = mrow >> 12, ntok = mrow & 4095;
          D0h[((size_t)((b * 8 + h) * 4096 + ntok)) * 96 + d] =
              f2bf(acc[mt][nt][r] + bi);
        }
      }
  } else {
    #pragma unroll
    for (int mt = 0; mt < 4; ++mt)
      #pragma unroll
      for (int nt = 0; nt < 4; ++nt) {
        int ncol = n0 + wc * 64 + nt * 16 + c;
        float bi = bias0[ncol];
        #pragma unroll
        for (int r = 0; r < 4; ++r) {
          int mrow = m0 + wr * 64 + mt * 16 + g * 4 + r;
          Out[(size_t)mrow * 768 + ncol] = acc[mt][nt][r] + bi;
        }
      }
  }
}

// ------------- flash attention: 4 waves x 32 q = 128 q per block -------------
// KV tiles of 64. E = Qh.Kh + Ql.Kh + Qh.Kl (f32-exact). Lane owns q-col (c) for
// 2 q-column blocks. K tiles DMA'd to linear [64][96]; Vt tile [96][64] with
// XOR chunk swizzle (^= d&7): linear DMA dest + pre-swizzled global source.
__global__ __launch_bounds__(256) void k_attn(
    const u16* __restrict__ Qh, const u16* __restrict__ Ql,
    const u16* __restrict__ Kh, const u16* __restrict__ Kl,
    const u16* __restrict__ Vt, u16* __restrict__ attn) {
  __shared__ __align__(16) u16 Klds[2][64 * 96];   // [0]=Kh,[1]=Kl; epilogue: O[128][96]
  __shared__ __align__(16) u16 Vtlds[96 * 64];     // swizzled
  __shared__ __align__(16) u16 Plds[4][2][16 * 72];

  const int bid = blockIdx.x;
  const int bh = bid >> 5, qb = bid & 31;
  const int t = threadIdx.x, w = t >> 6, lane = t & 63;
  const int g = lane >> 4, c = lane & 15;
  const int q0 = qb * 128;

  // Q fragments for this wave's 2 q-col blocks (lane holds Q[q = qc*16+c][d-chunk])
  u16x8 qfh[3][2], qfl[3][2];
  #pragma unroll
  for (int qc = 0; qc < 2; ++qc) {
    const size_t qoff = ((size_t)bh * 4096 + q0 + w * 32 + qc * 16 + c) * 96;
    #pragma unroll
    for (int kc = 0; kc < 3; ++kc) {
      qfh[kc][qc] = *(const u16x8*)(Qh + qoff + kc * 32 + g * 8);
      qfl[kc][qc] = *(const u16x8*)(Ql + qoff + kc * 32 + g * 8);
    }
  }

  f32x4 acc_o[6][2] = {};              // out^T[d = dt*16+g*4+r][q = qc*16+c]
  float m[2] = {-1e30f, -1e30f}, s[2] = {0.f, 0.f};

  const u16* Khb = Kh + (size_t)bh * 4096 * 96;
  const u16* Klb = Kl + (size_t)bh * 4096 * 96;
  const u16* Vtb = Vt + (size_t)bh * 96 * 4096;

  #pragma unroll 1
  for (int kv0 = 0; kv0 < 4096; kv0 += 64) {
    __syncthreads();
    // --- DMA staging: K tiles linear [64][96]; Vt [96][64] chunk-swizzled ---
    #pragma unroll
    for (int ii = 0; ii < 3; ++ii) {
      int i = t + 256 * ii;                 // 16B chunk id
      int lbase = (i & ~63) * 8;            // wave-uniform u16 offset
      GLD16(Khb + (size_t)kv0 * 96 + (size_t)i * 8, &Klds[0][lbase]);
      GLD16(Klb + (size_t)kv0 * 96 + (size_t)i * 8, &Klds[1][lbase]);
      // Vt: LDS linear pos i -> logical d = i>>3, chunk c8 = i&7; source
      // pre-swizzled so reader's (chunk ^ (d&7)) lands right.
      int d = i >> 3, c8 = i & 7;
      GLD16(Vtb + (size_t)d * 4096 + kv0 + ((c8 ^ (d & 7)) * 8), &Vtlds[lbase]);
    }
    __syncthreads();   // drains vmcnt -> DMA data visible

    // --- energy^T: et[mt][qc] holds E^T[k = mt*16+g*4+r][q = qc*16+c] ---
    f32x4 et[4][2] = {};
    #pragma unroll
    for (int kc = 0; kc < 3; ++kc)
      #pragma unroll
      for (int mt = 0; mt < 4; ++mt) {
        u16x8 kfh = *(u16x8*)(&Klds[0][(mt * 16 + c) * 96 + kc * 32 + g * 8]);
        u16x8 kfl = *(u16x8*)(&Klds[1][(mt * 16 + c) * 96 + kc * 32 + g * 8]);
        #pragma unroll
        for (int qc = 0; qc < 2; ++qc) {
          et[mt][qc] = mfma16(kfh, qfh[kc][qc], et[mt][qc]);
          et[mt][qc] = mfma16(kfh, qfl[kc][qc], et[mt][qc]);
          et[mt][qc] = mfma16(kfl, qfh[kc][qc], et[mt][qc]);
        }
      }

    // --- online softmax (per-lane scalar state per q-col) ---
    #pragma unroll
    for (int qc = 0; qc < 2; ++qc) {
      float tmax = -1e30f;
      #pragma unroll
      for (int mt = 0; mt < 4; ++mt)
        #pragma unroll
        for (int r = 0; r < 4; ++r) tmax = fmaxf(tmax, et[mt][qc][r]);
      tmax = fmaxf(tmax, __shfl_xor(tmax, 16));
      tmax = fmaxf(tmax, __shfl_xor(tmax, 32));
      float mnew = fmaxf(m[qc], tmax);
      float scale = __expf(m[qc] - mnew);
      float psum = 0.f;
      #pragma unroll
      for (int mt = 0; mt < 4; ++mt)
        #pragma unroll
        for (int r = 0; r < 4; ++r) {
          float p = __expf(et[mt][qc][r] - mnew);
          et[mt][qc][r] = p; psum += p;
        }
      psum += __shfl_xor(psum, 16);
      psum += __shfl_xor(psum, 32);
      s[qc] = s[qc] * scale + psum;
      m[qc] = mnew;
      #pragma unroll
      for (int dt = 0; dt < 6; ++dt)
        #pragma unroll
        for (int r = 0; r < 4; ++r) acc_o[dt][qc][r] *= scale;

      // P (bf16) -> per-wave per-qc LDS [16 q][64 k]
      u16* P = &Plds[w][qc][0];
      #pragma unroll
      for (int mt = 0; mt < 4; ++mt)
        #pragma unroll
        for (int rp = 0; rp < 2; ++rp) {
          unsigned pk = (unsigned)f2bf(et[mt][qc][2 * rp]) |
                        ((unsigned)f2bf(et[mt][qc][2 * rp + 1]) << 16);
          *(unsigned*)(&P[c * 72 + mt * 16 + g * 4 + 2 * rp]) = pk;
        }
    }
    // PV B-fragments: lane holds P[k = kb*32+g*8+j][q = qc*16+c]
    u16x8 pf[2][2];
    #pragma unroll
    for (int qc = 0; qc < 2; ++qc)
      #pragma unroll
      for (int kb = 0; kb < 2; ++kb)
        pf[qc][kb] = *(u16x8*)(&Plds[w][qc][c * 72 + kb * 32 + g * 8]);
    // out^T += V^T * P   (Vt read with chunk swizzle ^ (c&7))
    #pragma unroll
    for (int dt = 0; dt < 6; ++dt)
      #pragma unroll
      for (int kb = 0; kb < 2; ++kb) {
        u16x8 vf = *(u16x8*)(&Vtlds[(dt * 16 + c) * 64 +
                                    (((kb * 4 + g) ^ (c & 7)) * 8)]);
        #pragma unroll
        for (int qc = 0; qc < 2; ++qc)
          acc_o[dt][qc] = mfma16(vf, pf[qc][kb], acc_o[dt][qc]);
      }
  }

  // reference: att = softmax(E)/sqrt(D)  ->  out = (O/s)/sqrt(96)
  __syncthreads();
  u16* O = &Klds[0][0];  // reuse as [128 q][96 d]
  #pragma unroll
  for (int qc = 0; qc < 2; ++qc) {
    const float inv = 1.0f / (s[qc] * 9.797958971132712f);
    #pragma unroll
    for (int dt = 0; dt < 6; ++dt)
      #pragma unroll
      for (int rp = 0; rp < 2; ++rp) {
        unsigned pk = (unsigned)f2bf(acc_o[dt][qc][2 * rp] * inv) |
                      ((unsigned)f2bf(acc_o[dt][qc][2 * rp + 1] * inv) << 16);
        *(unsigned*)(&O[(w * 32 + qc * 16 + c) * 96 + dt * 16 + g * 4 + 2 * rp]) = pk;
      }
  }
  __syncthreads();
  const int b = bh >> 3, h = bh & 7;
  #pragma unroll
  for (int ii = 0; ii < 6; ++ii) {
    int i = t + 256 * ii, r = i / 12, c8 = i % 12;
    u16x8 v = *(u16x8*)(&O[r * 96 + c8 * 8]);
    *(u16x8*)(attn + ((size_t)(b * 4096 + q0 + r)) * 768 + h * 96 + c8 * 8) = v;
  }
}

// ---------------------------------------------------------------------
extern "C" void kernel_launch(void* const* d_in, const int* in_sizes, int n_in,
                              void* d_out, int out_size, void* d_ws, size_t ws_size,
                              hipStream_t stream) {
  const float* x  = (const float*)d_in[0];
  const float* Wq = (const float*)d_in[1];
  const float* bq = (const float*)d_in[2];
  const float* Wk = (const float*)d_in[3];
  const float* bk = (const float*)d_in[4];
  const float* Wv = (const float*)d_in[5];
  const float* bv = (const float*)d_in[6];
  const float* Wo = (const float*)d_in[7];
  const float* bo = (const float*)d_in[8];
  float* out = (float*)d_out;

  char* ws = (char*)d_ws;
  size_t off = 0;
  auto alloc = [&](size_t bytes) {
    void* p = ws + off;
    off += (bytes + 1023) & ~(size_t)1023;
    return p;
  };
  const size_t SZ = (size_t)16 * 4096 * 96 * 2;      // 12.6 MB per [B,H,N,D] bf16
  u16* ax    = (u16*)alloc((size_t)8192 * 1536 * 2);
  u16* wqkT  = (u16*)alloc((size_t)2 * 768 * 2304 * 2);
  u16* wvT   = (u16*)alloc((size_t)768 * 768 * 2);
  u16* woT   = (u16*)alloc((size_t)768 * 768 * 2);
  u16* Qhb   = (u16*)alloc(SZ);
  u16* Qlb   = (u16*)alloc(SZ);
  u16* Khb   = (u16*)alloc(SZ);
  u16* Klb   = (u16*)alloc(SZ);
  u16* Vb    = (u16*)alloc(SZ);
  u16* Vtb   = (u16*)alloc(SZ);
  u16* attnb = (u16*)alloc(SZ);
  (void)ws_size; (void)in_sizes; (void)n_in; (void)out_size;

  k_cast<<<3072, 256, 0, stream>>>(x, ax, 786432);
  k_wt<<<576, 256, 0, stream>>>(Wq, Wk, Wv, Wo, wqkT, wvT, woT);
  k_gemm<0><<<dim3(64, 12), 256, 0, stream>>>(ax, wqkT, bq, bk,
                                              Qhb, Qlb, Khb, Klb, nullptr);
  k_gemm<1><<<dim3(64, 6), 256, 0, stream>>>(ax, wvT, bv, nullptr,
                                             Vb, nullptr, nullptr, nullptr, nullptr);
  k_vt<<<1024, 256, 0, stream>>>(Vb, Vtb);
  k_attn<<<512, 256, 0, stream>>>(Qhb, Qlb, Khb, Klb, Vtb, attnb);
  k_gemm<2><<<dim3(64, 6), 256, 0, stream>>>(attnb, woT, bo, nullptr,
                                             nullptr, nullptr, nullptr, nullptr, out);
}

// Round 6
// 334.214 us; speedup vs baseline: 2.2254x; 1.3280x over previous
//
#include <hip/hip_runtime.h>
#include <hip/hip_bf16.h>

// MHA forward: B=2, N=4096, E=768, H=8, D=96. All-fp16 datapath (f32 accum):
// fp16 rounding is 8x finer than bf16 -> energy error ~0.004 abs (calibrated
// vs measured bf16 run), well inside threshold. R6: 1-term energy, single K
// staging (stride-104 bank-uniform), u64 P writes (stride 80), 3 blocks/CU.

typedef unsigned short u16;
typedef unsigned long long u64;
typedef __attribute__((ext_vector_type(4))) float f32x4;
typedef __attribute__((ext_vector_type(8))) _Float16 h16x8;
typedef __attribute__((ext_vector_type(8))) u16 u16x8;

#define DEVI static __device__ __forceinline__

// global->LDS DMA, 16B per lane; LDS dest = wave-uniform base + lane*16 (m104)
#define GLD16(gp, lp)                                                          \
  __builtin_amdgcn_global_load_lds(                                            \
      (const __attribute__((address_space(1))) void*)(gp),                     \
      (__attribute__((address_space(3))) void*)(lp), 16, 0, 0)

DEVI u16 f2h(float f) {
  _Float16 h = (_Float16)f;           // v_cvt_f16_f32, RNE
  return __builtin_bit_cast(u16, h);
}

DEVI f32x4 mfma16(u16x8 a, u16x8 b, f32x4 c) {
  return __builtin_amdgcn_mfma_f32_16x16x32_f16(
      __builtin_bit_cast(h16x8, a), __builtin_bit_cast(h16x8, b), c, 0, 0, 0);
}

// ---------------- cast x (f32 -> fp16), 8 elems/thread ----------------
__global__ void k_cast(const float* __restrict__ x, u16* __restrict__ xh, int n8) {
  int i = blockIdx.x * blockDim.x + threadIdx.x;
  if (i >= n8) return;
  const f32x4* p = (const f32x4*)x + (size_t)i * 2;
  f32x4 a = p[0], b = p[1];
  u16x8 o;
  #pragma unroll
  for (int u = 0; u < 4; ++u) { o[u] = f2h(a[u]); o[4 + u] = f2h(b[u]); }
  *((u16x8*)xh + i) = o;
}

// ------------- weight transpose+cast: wT[mat][n][k] = W[k][n], f32->fp16 -------------
__global__ void k_wt(const float* __restrict__ Wq, const float* __restrict__ Wk,
                     const float* __restrict__ Wv, const float* __restrict__ Wo,
                     u16* __restrict__ wT) {
  __shared__ __align__(16) float T[64 * 68];
  int bid = blockIdx.x;
  int mat = bid / 144, tt = bid % 144;
  int tr = tt / 12, tc = tt % 12;            // tr: k-tile, tc: n-tile
  const float* W = (mat == 0) ? Wq : (mat == 1) ? Wk : (mat == 2) ? Wv : Wo;
  int k0 = tr * 64, n0 = tc * 64;
  int t = threadIdx.x;
  #pragma unroll
  for (int ii = 0; ii < 4; ++ii) {
    int i = t + 256 * ii, r = i >> 4, c4 = i & 15;
    f32x4 v = *(const f32x4*)(W + (size_t)(k0 + r) * 768 + n0 + c4 * 4);
    *(f32x4*)(&T[r * 68 + c4 * 4]) = v;
  }
  __syncthreads();
  #pragma unroll
  for (int ii = 0; ii < 2; ++ii) {
    int i = t + 256 * ii, nn = i & 63, kc8 = i >> 6;
    u16x8 o;
    #pragma unroll
    for (int u = 0; u < 8; ++u) o[u] = f2h(T[(kc8 * 8 + u) * 68 + nn]);
    *(u16x8*)(wT + (size_t)mat * 589824 + (size_t)(n0 + nn) * 768 + k0 + kc8 * 8) = o;
  }
}

// ------------- V [BH][N][D] -> Vt [BH][D][N] (u16 passthrough) -------------
__global__ void k_vt(const u16* __restrict__ V, u16* __restrict__ Vt) {
  __shared__ __align__(16) u16 L[64 * 104];
  int bid = blockIdx.x, bh = bid >> 6, nb = bid & 63;
  int n0 = nb * 64, t = threadIdx.x;
  const u16* src = V + ((size_t)bh * 4096 + n0) * 96;
  #pragma unroll
  for (int ii = 0; ii < 3; ++ii) {
    int i = t + 256 * ii, r = i / 12, c8 = i % 12;
    *(u16x8*)(&L[r * 104 + c8 * 8]) = *(const u16x8*)(src + (size_t)i * 8);
  }
  __syncthreads();
  #pragma unroll
  for (int jj = 0; jj < 3; ++jj) {
    int d = (t & 31) + 32 * jj, c8 = t >> 5;
    u16x8 o;
    #pragma unroll
    for (int u = 0; u < 8; ++u) o[u] = L[(c8 * 8 + u) * 104 + d];
    *(u16x8*)(Vt + ((size_t)bh * 96 + d) * 4096 + n0 + c8 * 8) = o;
  }
}

// ------------- GEMM: 128x128 tile, BK=32, 4 waves, DMA staging, fp16 -------------
// MODE 0: QKV  A=xh[8192][768], BT=wT[2304][768] -> Qb/Kb/Vb fp16 [B,H,N,D] +bias
// MODE 1: out  A=attnb[8192][768], BT=woT[768][768] -> f32 Out +bias
template <int MODE>
__global__ __launch_bounds__(256) void k_gemm(
    const u16* __restrict__ A, const u16* __restrict__ BT,
    const float* __restrict__ bias0, const float* __restrict__ bias1,
    const float* __restrict__ bias2,
    u16* __restrict__ Qb, u16* __restrict__ Kb, u16* __restrict__ Vb,
    float* __restrict__ Out) {
  __shared__ __align__(16) u16 Alds[128 * 32];   // linear, DMA-staged
  __shared__ __align__(16) u16 Blds[128 * 32];
  const int m0 = blockIdx.x * 128, n0 = blockIdx.y * 128;
  const int t = threadIdx.x, w = t >> 6, lane = t & 63;
  const int g = lane >> 4, c = lane & 15;
  const int wr = w >> 1, wc = w & 1;

  f32x4 acc[4][4] = {};

  for (int k0 = 0; k0 < 768; k0 += 32) {
    __syncthreads();
    #pragma unroll
    for (int ii = 0; ii < 2; ++ii) {
      int i = t + 256 * ii;                 // 16B chunk id; row = i>>2, c8 = i&3
      int lbase = (i & ~63) * 8;            // wave-uniform u16 offset
      GLD16(A + (size_t)(m0 + (i >> 2)) * 768 + k0 + (i & 3) * 8, &Alds[lbase]);
      GLD16(BT + (size_t)(n0 + (i >> 2)) * 768 + k0 + (i & 3) * 8, &Blds[lbase]);
    }
    __syncthreads();
    u16x8 af[4], bf[4];
    #pragma unroll
    for (int mt = 0; mt < 4; ++mt)
      af[mt] = *(u16x8*)(&Alds[(wr * 64 + mt * 16 + c) * 32 + g * 8]);
    #pragma unroll
    for (int nt = 0; nt < 4; ++nt)
      bf[nt] = *(u16x8*)(&Blds[(wc * 64 + nt * 16 + c) * 32 + g * 8]);
    #pragma unroll
    for (int mt = 0; mt < 4; ++mt)
      #pragma unroll
      for (int nt = 0; nt < 4; ++nt)
        acc[mt][nt] = mfma16(af[mt], bf[nt], acc[mt][nt]);
  }

  // C layout per 16x16 tile: col = lane&15, row = (lane>>4)*4 + reg  [m89/m91]
  if (MODE == 0) {
    const int mat = n0 / 768;                       // 768 = 6*128, never straddles
    const float* bias = (mat == 0) ? bias0 : (mat == 1) ? bias1 : bias2;
    u16* dst = (mat == 0) ? Qb : (mat == 1) ? Kb : Vb;
    const int nbase = n0 - mat * 768;
    #pragma unroll
    for (int mt = 0; mt < 4; ++mt)
      #pragma unroll
      for (int nt = 0; nt < 4; ++nt) {
        int ncol = nbase + wc * 64 + nt * 16 + c;
        int h = ncol / 96, d = ncol % 96;           // 16-col run stays in one head
        float bi = bias[ncol];
        #pragma unroll
        for (int r = 0; r < 4; ++r) {
          int mrow = m0 + wr * 64 + mt * 16 + g * 4 + r;
          int b = mrow >> 12, ntok = mrow & 4095;
          dst[((size_t)((b * 8 + h) * 4096 + ntok)) * 96 + d] =
              f2h(acc[mt][nt][r] + bi);
        }
      }
  } else {
    #pragma unroll
    for (int mt = 0; mt < 4; ++mt)
      #pragma unroll
      for (int nt = 0; nt < 4; ++nt) {
        int ncol = n0 + wc * 64 + nt * 16 + c;
        float bi = bias0[ncol];
        #pragma unroll
        for (int r = 0; r < 4; ++r) {
          int mrow = m0 + wr * 64 + mt * 16 + g * 4 + r;
          Out[(size_t)mrow * 768 + ncol] = acc[mt][nt][r] + bi;
        }
      }
  }
}

// ------------- flash attention: 4 waves x 32 q = 128 q per block, fp16 -------------
// KV tiles of 64. E = K.Q^T via mfma(A=K, B=Q); lane owns q-col (c) for 2 q-blocks.
// K tile [64][104] (13 chunks/row: bank-uniform reads, DMA source clamped);
// Vt tile [96][64] XOR chunk swizzle; P [16][80] u64 writes (conflict-free).
__global__ __launch_bounds__(256) void k_attn(
    const u16* __restrict__ Q, const u16* __restrict__ K,
    const u16* __restrict__ Vt, u16* __restrict__ attn) {
  __shared__ __align__(16) u16 smem[23040];        // 46080 B -> 3 blocks/CU
  u16* Klds  = smem;                               // [64][104]
  u16* Vtlds = smem + 6656;                        // [96][64] swizzled
  u16* Plds  = smem + 12800;                       // [4][2][16][80]

  const int bid = blockIdx.x;
  const int bh = bid >> 5, qb = bid & 31;
  const int t = threadIdx.x, w = t >> 6, lane = t & 63;
  const int g = lane >> 4, c = lane & 15;
  const int q0 = qb * 128;

  // Q fragments (B-operand: lane holds Q[q = qc*16+c][d-chunk])
  u16x8 qf[3][2];
  #pragma unroll
  for (int qc = 0; qc < 2; ++qc) {
    const size_t qoff = ((size_t)bh * 4096 + q0 + w * 32 + qc * 16 + c) * 96;
    #pragma unroll
    for (int kc = 0; kc < 3; ++kc)
      qf[kc][qc] = *(const u16x8*)(Q + qoff + kc * 32 + g * 8);
  }

  f32x4 acc_o[6][2] = {};              // out^T[d = dt*16+g*4+r][q = qc*16+c]
  float m[2] = {-1e30f, -1e30f}, s[2] = {0.f, 0.f};

  const u16* Kbb = K + (size_t)bh * 4096 * 96;
  const u16* Vtb = Vt + (size_t)bh * 96 * 4096;

  #pragma unroll 1
  for (int kv0 = 0; kv0 < 4096; kv0 += 64) {
    __syncthreads();
    // K: 64 rows x 13 chunks = 832 chunks; last iter is wave 0 only (uniform)
    #pragma unroll
    for (int ii = 0; ii < 4; ++ii) {
      int i = t + 256 * ii;
      if (i < 832) {
        int row = i / 13, c8 = i % 13;
        int c8s = (c8 < 12) ? c8 : 0;            // pad chunk: harmless in-bounds src
        GLD16(Kbb + (size_t)(kv0 + row) * 96 + c8s * 8, &Klds[(i & ~63) * 8]);
      }
    }
    // Vt: 96 rows x 8 chunks, source pre-swizzled (chunk ^ (d&7))
    #pragma unroll
    for (int ii = 0; ii < 3; ++ii) {
      int i = t + 256 * ii, d = i >> 3, c8 = i & 7;
      GLD16(Vtb + (size_t)d * 4096 + kv0 + ((c8 ^ (d & 7)) * 8), &Vtlds[(i & ~63) * 8]);
    }
    __syncthreads();   // drains vmcnt -> DMA data visible

    // energy^T: et[mt][qc] holds E^T[k = mt*16+g*4+r][q = qc*16+c]
    f32x4 et[4][2] = {};
    #pragma unroll
    for (int kc = 0; kc < 3; ++kc)
      #pragma unroll
      for (int mt = 0; mt < 4; ++mt) {
        u16x8 kf = *(u16x8*)(&Klds[(mt * 16 + c) * 104 + kc * 32 + g * 8]);
        #pragma unroll
        for (int qc = 0; qc < 2; ++qc)
          et[mt][qc] = mfma16(kf, qf[kc][qc], et[mt][qc]);
      }

    // online softmax (per-lane scalar state per q-col)
    #pragma unroll
    for (int qc = 0; qc < 2; ++qc) {
      float tmax = -1e30f;
      #pragma unroll
      for (int mt = 0; mt < 4; ++mt)
        #pragma unroll
        for (int r = 0; r < 4; ++r) tmax = fmaxf(tmax, et[mt][qc][r]);
      tmax = fmaxf(tmax, __shfl_xor(tmax, 16));
      tmax = fmaxf(tmax, __shfl_xor(tmax, 32));
      float mnew = fmaxf(m[qc], tmax);
      float scale = __expf(m[qc] - mnew);
      float psum = 0.f;
      #pragma unroll
      for (int mt = 0; mt < 4; ++mt)
        #pragma unroll
        for (int r = 0; r < 4; ++r) {
          float p = __expf(et[mt][qc][r] - mnew);
          et[mt][qc][r] = p; psum += p;
        }
      psum += __shfl_xor(psum, 16);
      psum += __shfl_xor(psum, 32);
      s[qc] = s[qc] * scale + psum;
      m[qc] = mnew;
      #pragma unroll
      for (int dt = 0; dt < 6; ++dt)
        #pragma unroll
        for (int r = 0; r < 4; ++r) acc_o[dt][qc][r] *= scale;

      // P (fp16) -> per-wave per-qc LDS [16 q][64 k], one u64 per mt
      u16* P = Plds + (w * 2 + qc) * 1280;
      #pragma unroll
      for (int mt = 0; mt < 4; ++mt) {
        unsigned p0 = (unsigned)f2h(et[mt][qc][0]) |
                      ((unsigned)f2h(et[mt][qc][1]) << 16);
        unsigned p1 = (unsigned)f2h(et[mt][qc][2]) |
                      ((unsigned)f2h(et[mt][qc][3]) << 16);
        *(u64*)(&P[c * 80 + mt * 16 + g * 4]) = (u64)p0 | ((u64)p1 << 32);
      }
    }
    // PV B-fragments: lane holds P[k = kb*32+g*8+j][q = qc*16+c]
    u16x8 pf[2][2];
    #pragma unroll
    for (int qc = 0; qc < 2; ++qc)
      #pragma unroll
      for (int kb = 0; kb < 2; ++kb)
        pf[qc][kb] = *(u16x8*)(&Plds[(w * 2 + qc) * 1280 + c * 80 + kb * 32 + g * 8]);
    // out^T += V^T * P   (Vt read with chunk swizzle ^ (c&7))
    #pragma unroll
    for (int dt = 0; dt < 6; ++dt)
      #pragma unroll
      for (int kb = 0; kb < 2; ++kb) {
        u16x8 vf = *(u16x8*)(&Vtlds[(dt * 16 + c) * 64 +
                                    (((kb * 4 + g) ^ (c & 7)) * 8)]);
        #pragma unroll
        for (int qc = 0; qc < 2; ++qc)
          acc_o[dt][qc] = mfma16(vf, pf[qc][kb], acc_o[dt][qc]);
      }
  }

  // reference: att = softmax(E)/sqrt(D)  ->  out = (O/s)/sqrt(96)
  __syncthreads();
  u16* O = smem;  // reuse as [128 q][96 d]
  #pragma unroll
  for (int qc = 0; qc < 2; ++qc) {
    const float inv = 1.0f / (s[qc] * 9.797958971132712f);
    #pragma unroll
    for (int dt = 0; dt < 6; ++dt)
      #pragma unroll
      for (int rp = 0; rp < 2; ++rp) {
        unsigned pk = (unsigned)f2h(acc_o[dt][qc][2 * rp] * inv) |
                      ((unsigned)f2h(acc_o[dt][qc][2 * rp + 1] * inv) << 16);
        *(unsigned*)(&O[(w * 32 + qc * 16 + c) * 96 + dt * 16 + g * 4 + 2 * rp]) = pk;
      }
  }
  __syncthreads();
  const int b = bh >> 3, h = bh & 7;
  #pragma unroll
  for (int ii = 0; ii < 6; ++ii) {
    int i = t + 256 * ii, r = i / 12, c8 = i % 12;
    u16x8 v = *(u16x8*)(&O[r * 96 + c8 * 8]);
    *(u16x8*)(attn + ((size_t)(b * 4096 + q0 + r)) * 768 + h * 96 + c8 * 8) = v;
  }
}

// ---------------------------------------------------------------------
extern "C" void kernel_launch(void* const* d_in, const int* in_sizes, int n_in,
                              void* d_out, int out_size, void* d_ws, size_t ws_size,
                              hipStream_t stream) {
  const float* x  = (const float*)d_in[0];
  const float* Wq = (const float*)d_in[1];
  const float* bq = (const float*)d_in[2];
  const float* Wk = (const float*)d_in[3];
  const float* bk = (const float*)d_in[4];
  const float* Wv = (const float*)d_in[5];
  const float* bv = (const float*)d_in[6];
  const float* Wo = (const float*)d_in[7];
  const float* bo = (const float*)d_in[8];
  float* out = (float*)d_out;

  char* ws = (char*)d_ws;
  size_t off = 0;
  auto alloc = [&](size_t bytes) {
    void* p = ws + off;
    off += (bytes + 1023) & ~(size_t)1023;
    return p;
  };
  const size_t SZ = (size_t)16 * 4096 * 96 * 2;      // 12.6 MB per [B,H,N,D] fp16
  u16* xh    = (u16*)alloc((size_t)8192 * 768 * 2);
  u16* wT    = (u16*)alloc((size_t)4 * 768 * 768 * 2);
  u16* Qb    = (u16*)alloc(SZ);
  u16* Kb    = (u16*)alloc(SZ);
  u16* Vb    = (u16*)alloc(SZ);
  u16* Vtb   = (u16*)alloc(SZ);
  u16* attnb = (u16*)alloc(SZ);
  (void)ws_size; (void)in_sizes; (void)n_in; (void)out_size;

  k_cast<<<3072, 256, 0, stream>>>(x, xh, 786432);
  k_wt<<<576, 256, 0, stream>>>(Wq, Wk, Wv, Wo, wT);
  k_gemm<0><<<dim3(64, 18), 256, 0, stream>>>(xh, wT, bq, bk, bv,
                                              Qb, Kb, Vb, nullptr);
  k_vt<<<1024, 256, 0, stream>>>(Vb, Vtb);
  k_attn<<<512, 256, 0, stream>>>(Qb, Kb, Vtb, attnb);
  k_gemm<1><<<dim3(64, 6), 256, 0, stream>>>(attnb, wT + (size_t)3 * 589824,
                                             bo, nullptr, nullptr,
                                             nullptr, nullptr, nullptr, out);
}

// Round 9
// 314.254 us; speedup vs baseline: 2.3667x; 1.0635x over previous
//
#include <hip/hip_runtime.h>
#include <hip/hip_bf16.h>

// MHA forward: B=2, N=4096, E=768, H=8, D=96. All-fp16 datapath (f32 accum).
// R8 = R7 + pkrtz type fix: 2-phase pipelined staging (counted vmcnt(6), raw
// s_barrier, K/Vt dbuf), log2-domain softmax (Q pre-scaled by log2e),
// defer-max THR=12, cvt_pkrtz P-pack.

typedef unsigned short u16;
typedef unsigned long long u64;
typedef __attribute__((ext_vector_type(4))) float f32x4;
typedef __attribute__((ext_vector_type(8))) _Float16 h16x8;
typedef __attribute__((ext_vector_type(2))) __fp16 fp16x2;   // cvt_pkrtz native type
typedef __attribute__((ext_vector_type(8))) u16 u16x8;

#define DEVI static __device__ __forceinline__

// global->LDS DMA, 16B/lane; LDS dest = wave-uniform base + lane*16 (m104)
#define GLD16(gp, lp)                                                          \
  __builtin_amdgcn_global_load_lds(                                            \
      (const __attribute__((address_space(1))) void*)(gp),                     \
      (__attribute__((address_space(3))) void*)(lp), 16, 0, 0)
#define VM_WAIT6() asm volatile("s_waitcnt vmcnt(6)" ::: "memory")
#define VM_WAIT4() asm volatile("s_waitcnt vmcnt(4)" ::: "memory")
#define VM_WAIT0() asm volatile("s_waitcnt vmcnt(0)" ::: "memory")
#define BARRAW()   asm volatile("s_barrier" ::: "memory")

DEVI u16 f2h(float f) {
  _Float16 h = (_Float16)f;           // v_cvt_f16_f32, RNE
  return __builtin_bit_cast(u16, h);
}

DEVI unsigned pkrtz(float a, float b) {
  fp16x2 h = __builtin_amdgcn_cvt_pkrtz(a, b);   // v_cvt_pkrtz_f16_f32
  return __builtin_bit_cast(unsigned, h);
}

DEVI float exp2fast(float x) {
#if __has_builtin(__builtin_amdgcn_exp2f)
  return __builtin_amdgcn_exp2f(x);
#else
  return __expf(x * 0.6931471805599453f);
#endif
}

DEVI f32x4 mfma16(u16x8 a, u16x8 b, f32x4 c) {
  return __builtin_amdgcn_mfma_f32_16x16x32_f16(
      __builtin_bit_cast(h16x8, a), __builtin_bit_cast(h16x8, b), c, 0, 0, 0);
}

// ---------------- cast x (f32 -> fp16), 8 elems/thread ----------------
__global__ void k_cast(const float* __restrict__ x, u16* __restrict__ xh, int n8) {
  int i = blockIdx.x * blockDim.x + threadIdx.x;
  if (i >= n8) return;
  const f32x4* p = (const f32x4*)x + (size_t)i * 2;
  f32x4 a = p[0], b = p[1];
  u16x8 o;
  #pragma unroll
  for (int u = 0; u < 4; ++u) { o[u] = f2h(a[u]); o[4 + u] = f2h(b[u]); }
  *((u16x8*)xh + i) = o;
}

// ------------- weight transpose+cast: wT[mat][n][k] = W[k][n], f32->fp16 -------------
__global__ void k_wt(const float* __restrict__ Wq, const float* __restrict__ Wk,
                     const float* __restrict__ Wv, const float* __restrict__ Wo,
                     u16* __restrict__ wT) {
  __shared__ __align__(16) float T[64 * 68];
  int bid = blockIdx.x;
  int mat = bid / 144, tt = bid % 144;
  int tr = tt / 12, tc = tt % 12;            // tr: k-tile, tc: n-tile
  const float* W = (mat == 0) ? Wq : (mat == 1) ? Wk : (mat == 2) ? Wv : Wo;
  int k0 = tr * 64, n0 = tc * 64;
  int t = threadIdx.x;
  #pragma unroll
  for (int ii = 0; ii < 4; ++ii) {
    int i = t + 256 * ii, r = i >> 4, c4 = i & 15;
    f32x4 v = *(const f32x4*)(W + (size_t)(k0 + r) * 768 + n0 + c4 * 4);
    *(f32x4*)(&T[r * 68 + c4 * 4]) = v;
  }
  __syncthreads();
  #pragma unroll
  for (int ii = 0; ii < 2; ++ii) {
    int i = t + 256 * ii, nn = i & 63, kc8 = i >> 6;
    u16x8 o;
    #pragma unroll
    for (int u = 0; u < 8; ++u) o[u] = f2h(T[(kc8 * 8 + u) * 68 + nn]);
    *(u16x8*)(wT + (size_t)mat * 589824 + (size_t)(n0 + nn) * 768 + k0 + kc8 * 8) = o;
  }
}

// ------------- V [BH][N][D] -> Vt [BH][D][N] (u16 passthrough) -------------
__global__ void k_vt(const u16* __restrict__ V, u16* __restrict__ Vt) {
  __shared__ __align__(16) u16 L[64 * 104];
  int bid = blockIdx.x, bh = bid >> 6, nb = bid & 63;
  int n0 = nb * 64, t = threadIdx.x;
  const u16* src = V + ((size_t)bh * 4096 + n0) * 96;
  #pragma unroll
  for (int ii = 0; ii < 3; ++ii) {
    int i = t + 256 * ii, r = i / 12, c8 = i % 12;
    *(u16x8*)(&L[r * 104 + c8 * 8]) = *(const u16x8*)(src + (size_t)i * 8);
  }
  __syncthreads();
  #pragma unroll
  for (int jj = 0; jj < 3; ++jj) {
    int d = (t & 31) + 32 * jj, c8 = t >> 5;
    u16x8 o;
    #pragma unroll
    for (int u = 0; u < 8; ++u) o[u] = L[(c8 * 8 + u) * 104 + d];
    *(u16x8*)(Vt + ((size_t)bh * 96 + d) * 4096 + n0 + c8 * 8) = o;
  }
}

// ------------- GEMM: 128x128 tile, BK=32, 4 waves, 2-phase pipelined DMA -------------
// MODE 0: QKV  A=xh[8192][768], BT=wT[2304][768] -> Qb/Kb/Vb fp16 [B,H,N,D] +bias
//         (Q outputs scaled by log2e for log2-domain softmax)
// MODE 1: out  A=attnb[8192][768], BT=woT[768][768] -> f32 Out +bias
template <int MODE>
__global__ __launch_bounds__(256) void k_gemm(
    const u16* __restrict__ A, const u16* __restrict__ BT,
    const float* __restrict__ bias0, const float* __restrict__ bias1,
    const float* __restrict__ bias2,
    u16* __restrict__ Qb, u16* __restrict__ Kb, u16* __restrict__ Vb,
    float* __restrict__ Out) {
  __shared__ __align__(16) u16 sg[16384];   // [buf][A:4096 | B:4096] u16
  const int m0 = blockIdx.x * 128, n0 = blockIdx.y * 128;
  const int t = threadIdx.x, w = t >> 6, lane = t & 63;
  const int g = lane >> 4, c = lane & 15;
  const int wr = w >> 1, wc = w & 1;

  const u16* ap[2]; const u16* bp[2]; int lo[2];
  #pragma unroll
  for (int ii = 0; ii < 2; ++ii) {
    int i = t + 256 * ii;
    ap[ii] = A + (size_t)(m0 + (i >> 2)) * 768 + (i & 3) * 8;
    bp[ii] = BT + (size_t)(n0 + (i >> 2)) * 768 + (i & 3) * 8;
    lo[ii] = (i & ~63) * 8;                 // wave-uniform u16 offset
  }
  auto STAGE = [&](int buf) {
    #pragma unroll
    for (int ii = 0; ii < 2; ++ii) {
      GLD16(ap[ii], &sg[buf * 4096 + lo[ii]]);
      GLD16(bp[ii], &sg[8192 + buf * 4096 + lo[ii]]);
      ap[ii] += 32; bp[ii] += 32;
    }
  };

  f32x4 acc[4][4] = {};
  STAGE(0);
  #pragma unroll 1
  for (int kk = 0; kk < 24; ++kk) {
    const int cur = kk & 1;
    if (kk < 23) { STAGE(cur ^ 1); VM_WAIT4(); } else { VM_WAIT0(); }
    BARRAW();
    u16x8 af[4], bf[4];
    #pragma unroll
    for (int mt = 0; mt < 4; ++mt)
      af[mt] = *(u16x8*)(&sg[cur * 4096 + (wr * 64 + mt * 16 + c) * 32 + g * 8]);
    #pragma unroll
    for (int nt = 0; nt < 4; ++nt)
      bf[nt] = *(u16x8*)(&sg[8192 + cur * 4096 + (wc * 64 + nt * 16 + c) * 32 + g * 8]);
    #pragma unroll
    for (int mt = 0; mt < 4; ++mt)
      #pragma unroll
      for (int nt = 0; nt < 4; ++nt)
        acc[mt][nt] = mfma16(af[mt], bf[nt], acc[mt][nt]);
    BARRAW();
  }

  // C layout per 16x16 tile: col = lane&15, row = (lane>>4)*4 + reg  [m89/m91]
  if (MODE == 0) {
    const int mat = n0 / 768;                       // never straddles
    const float* bias = (mat == 0) ? bias0 : (mat == 1) ? bias1 : bias2;
    u16* dst = (mat == 0) ? Qb : (mat == 1) ? Kb : Vb;
    const float qsc = (mat == 0) ? 1.44269504f : 1.0f;   // log2e into Q
    const int nbase = n0 - mat * 768;
    #pragma unroll
    for (int mt = 0; mt < 4; ++mt)
      #pragma unroll
      for (int nt = 0; nt < 4; ++nt) {
        int ncol = nbase + wc * 64 + nt * 16 + c;
        int h = ncol / 96, d = ncol % 96;           // 16-col run stays in one head
        float bi = bias[ncol];
        #pragma unroll
        for (int r = 0; r < 4; ++r) {
          int mrow = m0 + wr * 64 + mt * 16 + g * 4 + r;
          int b = mrow >> 12, ntok = mrow & 4095;
          dst[((size_t)((b * 8 + h) * 4096 + ntok)) * 96 + d] =
              f2h((acc[mt][nt][r] + bi) * qsc);
        }
      }
  } else {
    #pragma unroll
    for (int mt = 0; mt < 4; ++mt)
      #pragma unroll
      for (int nt = 0; nt < 4; ++nt) {
        int ncol = n0 + wc * 64 + nt * 16 + c;
        float bi = bias0[ncol];
        #pragma unroll
        for (int r = 0; r < 4; ++r) {
          int mrow = m0 + wr * 64 + mt * 16 + g * 4 + r;
          Out[(size_t)mrow * 768 + ncol] = acc[mt][nt][r] + bi;
        }
      }
  }
}

// ------------- flash attention: 4 waves x 32 q, 2-phase pipelined KV staging -------------
// Energies in log2 units (Q pre-scaled). E^T = mfma(A=K, B=Q); lane owns q-col c
// for 2 q-blocks. K dbuf [2][64][96] linear; Vt dbuf [2][96][64] XOR-chunk-swizzled
// via pre-swizzled global source; P [4][2][16][80] u64 writes. 69.6 KB LDS.
__global__ __launch_bounds__(256) void k_attn(
    const u16* __restrict__ Q, const u16* __restrict__ K,
    const u16* __restrict__ Vt, u16* __restrict__ attn) {
  __shared__ __align__(16) u16 smem[34816];
  // [0,12288): K bufs; [12288,24576): Vt bufs; [24576,34816): P

  const int bid = blockIdx.x;
  const int bh = bid >> 5, qb = bid & 31;
  const int t = threadIdx.x, w = t >> 6, lane = t & 63;
  const int g = lane >> 4, c = lane & 15;
  const int q0 = qb * 128;

  // Q fragments (B-operand: lane holds Q[q = qc*16+c][d-chunk]); log2e pre-folded
  u16x8 qf[3][2];
  #pragma unroll
  for (int qc = 0; qc < 2; ++qc) {
    const size_t qoff = ((size_t)bh * 4096 + q0 + w * 32 + qc * 16 + c) * 96;
    #pragma unroll
    for (int kc = 0; kc < 3; ++kc)
      qf[kc][qc] = *(const u16x8*)(Q + qoff + kc * 32 + g * 8);
  }
  VM_WAIT0();   // resolve Q before the counted-vmcnt pipeline starts

  const u16* Kbb = K + (size_t)bh * 4096 * 96;
  const u16* Vtb = Vt + (size_t)bh * 96 * 4096;
  const u16* ks[3]; const u16* vs[3]; int ko[3], vo[3];
  #pragma unroll
  for (int ii = 0; ii < 3; ++ii) {
    int ci = t + 256 * ii;                  // 16B chunk id, 768 chunks per tile
    ks[ii] = Kbb + ci * 8;                  // K tile is fully contiguous
    int d = ci >> 3, c8 = ci & 7;
    vs[ii] = Vtb + (size_t)d * 4096 + ((c8 ^ (d & 7)) * 8);  // pre-swizzled src
    ko[ii] = (ci & ~63) * 8;                // wave-uniform u16 offset
    vo[ii] = 12288 + (ci & ~63) * 8;
  }
  auto STAGE = [&](int buf) {
    #pragma unroll
    for (int ii = 0; ii < 3; ++ii) {
      GLD16(ks[ii], &smem[buf * 6144 + ko[ii]]);
      GLD16(vs[ii], &smem[buf * 6144 + vo[ii]]);
      ks[ii] += 6144;                       // next KV tile (64 rows x 96)
      vs[ii] += 64;                         // next 64 kv columns
    }
  };

  f32x4 acc_o[6][2] = {};              // out^T[d = dt*16+g*4+r][q = qc*16+c]
  float m[2] = {-1e30f, -1e30f}, s[2] = {0.f, 0.f};
  u16* Pw = &smem[24576 + w * 2560];   // this wave's P region [2][16][80]

  STAGE(0);
  #pragma unroll 1
  for (int tt = 0; tt < 64; ++tt) {
    const int cur = tt & 1;
    if (tt < 63) { STAGE(cur ^ 1); VM_WAIT6(); } else { VM_WAIT0(); }
    BARRAW();                               // all waves: tile tt staged
    const u16* Kl = &smem[cur * 6144];
    const u16* Vl = &smem[12288 + cur * 6144];

    // energy^T (log2 units): et[mt][qc] = E^T[k = mt*16+g*4+r][q = qc*16+c]
    f32x4 et[4][2] = {};
    #pragma unroll
    for (int kc = 0; kc < 3; ++kc)
      #pragma unroll
      for (int mt = 0; mt < 4; ++mt) {
        u16x8 kf = *(const u16x8*)(&Kl[(mt * 16 + c) * 96 + kc * 32 + g * 8]);
        et[mt][0] = mfma16(kf, qf[kc][0], et[mt][0]);
        et[mt][1] = mfma16(kf, qf[kc][1], et[mt][1]);
      }

    // online softmax, log2 domain, defer-max (THR=12 -> P <= 4096, fp16-safe)
    #pragma unroll
    for (int qc = 0; qc < 2; ++qc) {
      float t0 = fmaxf(fmaxf(et[0][qc][0], et[0][qc][1]),
                       fmaxf(et[0][qc][2], et[0][qc][3]));
      float t1 = fmaxf(fmaxf(et[1][qc][0], et[1][qc][1]),
                       fmaxf(et[1][qc][2], et[1][qc][3]));
      float t2 = fmaxf(fmaxf(et[2][qc][0], et[2][qc][1]),
                       fmaxf(et[2][qc][2], et[2][qc][3]));
      float t3 = fmaxf(fmaxf(et[3][qc][0], et[3][qc][1]),
                       fmaxf(et[3][qc][2], et[3][qc][3]));
      float tmax = fmaxf(fmaxf(t0, t1), fmaxf(t2, t3));
      tmax = fmaxf(tmax, __shfl_xor(tmax, 16));
      tmax = fmaxf(tmax, __shfl_xor(tmax, 32));
      bool upd = tmax > m[qc] + 12.0f;
      float mnew = upd ? tmax : m[qc];
      if (__any(upd)) {                     // skip rescale on most tiles
        float sc = exp2fast(m[qc] - mnew);  // ==1 for non-upd lanes
        s[qc] *= sc;
        #pragma unroll
        for (int dt = 0; dt < 6; ++dt)
          #pragma unroll
          for (int r = 0; r < 4; ++r) acc_o[dt][qc][r] *= sc;
      }
      m[qc] = mnew;
      float psum = 0.f;
      #pragma unroll
      for (int mt = 0; mt < 4; ++mt)
        #pragma unroll
        for (int r = 0; r < 4; ++r) {
          float p = exp2fast(et[mt][qc][r] - mnew);
          et[mt][qc][r] = p; psum += p;
        }
      psum += __shfl_xor(psum, 16);
      psum += __shfl_xor(psum, 32);
      s[qc] += psum;

      // P (fp16, RTZ pack) -> per-wave per-qc LDS [16 q][64 k]
      u16* P = Pw + qc * 1280;
      #pragma unroll
      for (int mt = 0; mt < 4; ++mt) {
        unsigned p0 = pkrtz(et[mt][qc][0], et[mt][qc][1]);
        unsigned p1 = pkrtz(et[mt][qc][2], et[mt][qc][3]);
        *(u64*)(&P[c * 80 + mt * 16 + g * 4]) = (u64)p0 | ((u64)p1 << 32);
      }
    }
    // PV B-fragments: lane holds P[k = kb*32+g*8+j][q = qc*16+c]
    u16x8 pf[2][2];
    #pragma unroll
    for (int qc = 0; qc < 2; ++qc)
      #pragma unroll
      for (int kb = 0; kb < 2; ++kb)
        pf[qc][kb] = *(u16x8*)(&Pw[qc * 1280 + c * 80 + kb * 32 + g * 8]);
    // out^T += V^T * P   (Vt read with chunk swizzle ^ (c&7))
    #pragma unroll
    for (int dt = 0; dt < 6; ++dt)
      #pragma unroll
      for (int kb = 0; kb < 2; ++kb) {
        u16x8 vf = *(u16x8*)(&Vl[(dt * 16 + c) * 64 + (((kb * 4 + g) ^ (c & 7)) * 8)]);
        acc_o[dt][0] = mfma16(vf, pf[0][kb], acc_o[dt][0]);
        acc_o[dt][1] = mfma16(vf, pf[1][kb], acc_o[dt][1]);
      }
    BARRAW();                               // all waves done reading buf[cur]
  }

  // reference: att = softmax(E)/sqrt(D)  ->  out = (O/s)/sqrt(96)
  __syncthreads();
  u16* O = smem;  // reuse as [128 q][96 d]
  #pragma unroll
  for (int qc = 0; qc < 2; ++qc) {
    const float inv = 1.0f / (s[qc] * 9.797958971132712f);
    #pragma unroll
    for (int dt = 0; dt < 6; ++dt)
      #pragma unroll
      for (int rp = 0; rp < 2; ++rp) {
        unsigned pk = (unsigned)f2h(acc_o[dt][qc][2 * rp] * inv) |
                      ((unsigned)f2h(acc_o[dt][qc][2 * rp + 1] * inv) << 16);
        *(unsigned*)(&O[(w * 32 + qc * 16 + c) * 96 + dt * 16 + g * 4 + 2 * rp]) = pk;
      }
  }
  __syncthreads();
  const int b = bh >> 3, h = bh & 7;
  #pragma unroll
  for (int ii = 0; ii < 6; ++ii) {
    int i = t + 256 * ii, r = i / 12, c8 = i % 12;
    u16x8 v = *(u16x8*)(&O[r * 96 + c8 * 8]);
    *(u16x8*)(attn + ((size_t)(b * 4096 + q0 + r)) * 768 + h * 96 + c8 * 8) = v;
  }
}

// ---------------------------------------------------------------------
extern "C" void kernel_launch(void* const* d_in, const int* in_sizes, int n_in,
                              void* d_out, int out_size, void* d_ws, size_t ws_size,
                              hipStream_t stream) {
  const float* x  = (const float*)d_in[0];
  const float* Wq = (const float*)d_in[1];
  const float* bq = (const float*)d_in[2];
  const float* Wk = (const float*)d_in[3];
  const float* bk = (const float*)d_in[4];
  const float* Wv = (const float*)d_in[5];
  const float* bv = (const float*)d_in[6];
  const float* Wo = (const float*)d_in[7];
  const float* bo = (const float*)d_in[8];
  float* out = (float*)d_out;

  char* ws = (char*)d_ws;
  size_t off = 0;
  auto alloc = [&](size_t bytes) {
    void* p = ws + off;
    off += (bytes + 1023) & ~(size_t)1023;
    return p;
  };
  const size_t SZ = (size_t)16 * 4096 * 96 * 2;      // 12.6 MB per [B,H,N,D] fp16
  u16* xh    = (u16*)alloc((size_t)8192 * 768 * 2);
  u16* wT    = (u16*)alloc((size_t)4 * 768 * 768 * 2);
  u16* Qb    = (u16*)alloc(SZ);
  u16* Kb    = (u16*)alloc(SZ);
  u16* Vb    = (u16*)alloc(SZ);
  u16* Vtb   = (u16*)alloc(SZ);
  u16* attnb = (u16*)alloc(SZ);
  (void)ws_size; (void)in_sizes; (void)n_in; (void)out_size;

  k_cast<<<3072, 256, 0, stream>>>(x, xh, 786432);
  k_wt<<<576, 256, 0, stream>>>(Wq, Wk, Wv, Wo, wT);
  k_gemm<0><<<dim3(64, 18), 256, 0, stream>>>(xh, wT, bq, bk, bv,
                                              Qb, Kb, Vb, nullptr);
  k_vt<<<1024, 256, 0, stream>>>(Vb, Vtb);
  k_attn<<<512, 256, 0, stream>>>(Qb, Kb, Vtb, attnb);
  k_gemm<1><<<dim3(64, 6), 256, 0, stream>>>(attnb, wT + (size_t)3 * 589824,
                                             bo, nullptr, nullptr,
                                             nullptr, nullptr, nullptr, out);
}